// Round 3
// baseline (1883.546 us; speedup 1.0000x reference)
//
#include <hip/hip_runtime.h>
#include <hip/hip_bf16.h>
#include <math.h>

#define NTOK 384
#define HEADS 4

typedef __attribute__((ext_vector_type(8))) short bf16x8;
typedef __attribute__((ext_vector_type(4))) float f32x4;

__device__ __forceinline__ unsigned short f2b(float f) {
    union { float f; unsigned int u; } v; v.f = f;
    unsigned int r = (v.u + 0x7fff + ((v.u >> 16) & 1)) >> 16;  // RNE
    return (unsigned short)r;
}

// pack hi16(x), hi16(y) with round-half-away: 3 VALU ops per 2 values
__device__ __forceinline__ unsigned int pk2(float x, float y) {
    unsigned int ux = __float_as_uint(x) + 0x8000u;
    unsigned int uy = __float_as_uint(y) + 0x8000u;
    return __builtin_amdgcn_perm(uy, ux, 0x07060302u);
}

// ---------------------------------------------------------------------------
// MFMA GEMM, A bf16 (MxK row-major), B fp32 (NxK row-major, ldb=K) converted
// inline to bf16. C = A@B^T + bias, optional relu, fp32 or bf16 out.
// Block 256 thr = 4 waves (2x2); block tile 128x128, wave tile 64x64
// (4x4 MFMA 16x16x32). Optional transposed-V epilogue for cols >= dv2.
// ---------------------------------------------------------------------------
__global__ __launch_bounds__(256, 2) void gemm_wf32(
    const unsigned short* __restrict__ A, const float* __restrict__ B,
    const float* __restrict__ bias, void* __restrict__ Cv,
    int K, int lda, int ldc, int relu, int out_bf16,
    unsigned short* __restrict__ vt, int dv2)
{
    const int lane = threadIdx.x & 63;
    const int wid  = threadIdx.x >> 6;
    const int wm = wid >> 1, wn = wid & 1;
    const int r16 = lane & 15, quad = lane >> 4;
    const int row0 = blockIdx.y * 128 + wm * 64;
    const int col0 = blockIdx.x * 128 + wn * 64;

    f32x4 acc[4][4] = {};

    const unsigned short* Ap = A + (long)(row0 + r16) * lda + quad * 8;
    const float* Bp = B + (long)(col0 + r16) * K + quad * 8;

    for (int k0 = 0; k0 < K; k0 += 32) {
        bf16x8 a[4];
        #pragma unroll
        for (int rt = 0; rt < 4; ++rt)
            a[rt] = *reinterpret_cast<const bf16x8*>(Ap + (long)rt * 16 * lda + k0);
        #pragma unroll
        for (int ct = 0; ct < 4; ++ct) {
            const float* bp = Bp + (long)ct * 16 * K + k0;
            float4 f0 = *reinterpret_cast<const float4*>(bp);
            float4 f1 = *reinterpret_cast<const float4*>(bp + 4);
            union { unsigned int u[4]; bf16x8 v; } bb;
            bb.u[0] = pk2(f0.x, f0.y);
            bb.u[1] = pk2(f0.z, f0.w);
            bb.u[2] = pk2(f1.x, f1.y);
            bb.u[3] = pk2(f1.z, f1.w);
            #pragma unroll
            for (int rt = 0; rt < 4; ++rt)
                acc[rt][ct] = __builtin_amdgcn_mfma_f32_16x16x32_bf16(
                    a[rt], bb.v, acc[rt][ct], 0, 0, 0);
        }
    }

    float* Cf = (float*)Cv;
    unsigned short* Cb = (unsigned short*)Cv;
    const int vwrite = (vt != nullptr) && (col0 >= dv2);
    #pragma unroll
    for (int rt = 0; rt < 4; ++rt) {
        #pragma unroll
        for (int ct = 0; ct < 4; ++ct) {
            f32x4 v = acc[rt][ct];
            int col = col0 + ct * 16 + r16;
            float bi = bias ? bias[col] : 0.f;
            #pragma unroll
            for (int i = 0; i < 4; ++i) {
                v[i] += bi;
                if (relu) v[i] = fmaxf(v[i], 0.f);
            }
            if (vwrite) {
                ushort4 p;
                p.x = f2b(v[0]); p.y = f2b(v[1]); p.z = f2b(v[2]); p.w = f2b(v[3]);
                *reinterpret_cast<ushort4*>(
                    vt + (long)(col - dv2) * NTOK + row0 + rt * 16 + quad * 4) = p;
            } else if (out_bf16) {
                #pragma unroll
                for (int i = 0; i < 4; ++i)
                    Cb[(long)(row0 + rt * 16 + quad * 4 + i) * ldc + col] = f2b(v[i]);
            } else {
                #pragma unroll
                for (int i = 0; i < 4; ++i)
                    Cf[(long)(row0 + rt * 16 + quad * 4 + i) * ldc + col] = v[i];
            }
        }
    }
}

// ---------------------------------------------------------------------------
// Fused attention: S = Q@K^T, softmax (in-register), O = P@V^T.
// Grid (NTOK/64, HEADS), block 256 = 4 waves; wave owns 16 q-rows x all 384.
// qkv: bf16 [NTOK][3d]; vt: bf16 [d][NTOK] (V transposed); o: bf16 [NTOK][d].
// ---------------------------------------------------------------------------
template <int HD>
__global__ __launch_bounds__(256, 1) void attn_fused(
    const unsigned short* __restrict__ qkv, const unsigned short* __restrict__ vt,
    unsigned short* __restrict__ o, float scale)
{
    constexpr int D = HD * HEADS;
    constexpr int LDQ = 3 * D;
    __shared__ unsigned short plds[4][16 * NTOK];

    const int lane = threadIdx.x & 63;
    const int w    = threadIdx.x >> 6;
    const int r16 = lane & 15, quad = lane >> 4;
    const int qbase = blockIdx.x * 64 + w * 16;
    const int h = blockIdx.y;

    // ---- phase 1: S = Q @ K^T  (16 x 384) ----
    f32x4 s[24] = {};
    const unsigned short* Qp = qkv + (long)(qbase + r16) * LDQ + h * HD + quad * 8;
    const unsigned short* Kp = qkv + D + h * HD + quad * 8;
    for (int k0 = 0; k0 < HD; k0 += 32) {
        bf16x8 qa = *reinterpret_cast<const bf16x8*>(Qp + k0);
        #pragma unroll
        for (int ct = 0; ct < 24; ++ct) {
            bf16x8 kb = *reinterpret_cast<const bf16x8*>(
                Kp + (long)(ct * 16 + r16) * LDQ + k0);
            s[ct] = __builtin_amdgcn_mfma_f32_16x16x32_bf16(qa, kb, s[ct], 0, 0, 0);
        }
    }

    // ---- softmax over 384 cols; row = quad*4+i, cols spread over 16 lanes ----
    float mrow[4] = {-1e30f, -1e30f, -1e30f, -1e30f};
    #pragma unroll
    for (int ct = 0; ct < 24; ++ct)
        #pragma unroll
        for (int i = 0; i < 4; ++i) mrow[i] = fmaxf(mrow[i], s[ct][i]);
    #pragma unroll
    for (int m = 1; m <= 8; m <<= 1)
        #pragma unroll
        for (int i = 0; i < 4; ++i) mrow[i] = fmaxf(mrow[i], __shfl_xor(mrow[i], m));
    float sum[4] = {};
    #pragma unroll
    for (int ct = 0; ct < 24; ++ct)
        #pragma unroll
        for (int i = 0; i < 4; ++i) {
            float e = __expf((s[ct][i] - mrow[i]) * scale);
            s[ct][i] = e; sum[i] += e;
        }
    #pragma unroll
    for (int m = 1; m <= 8; m <<= 1)
        #pragma unroll
        for (int i = 0; i < 4; ++i) sum[i] += __shfl_xor(sum[i], m);
    float inv[4];
    #pragma unroll
    for (int i = 0; i < 4; ++i) inv[i] = 1.f / sum[i];

    // P -> LDS, row-major [16][384] (A-fragment friendly)
    #pragma unroll
    for (int ct = 0; ct < 24; ++ct)
        #pragma unroll
        for (int i = 0; i < 4; ++i)
            plds[w][(quad * 4 + i) * NTOK + ct * 16 + r16] = f2b(s[ct][i] * inv[i]);
    __syncthreads();

    // ---- phase 2: O = P @ V^T  (16 x HD) ----
    f32x4 oa[HD / 16] = {};
    const unsigned short* Vp = vt + (long)(h * HD + r16) * NTOK + quad * 8;
    for (int k0 = 0; k0 < NTOK; k0 += 32) {
        bf16x8 pa = *reinterpret_cast<const bf16x8*>(
            &plds[w][r16 * NTOK + k0 + quad * 8]);
        #pragma unroll
        for (int ct = 0; ct < HD / 16; ++ct) {
            bf16x8 vb = *reinterpret_cast<const bf16x8*>(
                Vp + (long)ct * 16 * NTOK + k0);
            oa[ct] = __builtin_amdgcn_mfma_f32_16x16x32_bf16(pa, vb, oa[ct], 0, 0, 0);
        }
    }
    #pragma unroll
    for (int ct = 0; ct < HD / 16; ++ct)
        #pragma unroll
        for (int i = 0; i < 4; ++i)
            o[(long)(qbase + quad * 4 + i) * D + h * HD + ct * 16 + r16] =
                f2b(oa[ct][i]);
}

// ---------------------------------------------------------------------------
// x = LayerNorm(x + y) * s + b  (fp32), also writes bf16 copy xb.
// ---------------------------------------------------------------------------
__global__ __launch_bounds__(256) void add_ln(
    float* __restrict__ x, unsigned short* __restrict__ xb,
    const float* __restrict__ y,
    const float* __restrict__ s, const float* __restrict__ b, int d)
{
    float* xr = x + (long)blockIdx.x * d;
    unsigned short* xbr = xb + (long)blockIdx.x * d;
    const float* yr = y + (long)blockIdx.x * d;
    const int t = threadIdx.x;
    float s1 = 0.f, s2 = 0.f;
    for (int i = t; i < d; i += 256) {
        float v = xr[i] + yr[i];
        s1 += v; s2 += v * v;
    }
    for (int off = 32; off; off >>= 1) { s1 += __shfl_down(s1, off); s2 += __shfl_down(s2, off); }
    __shared__ float r1[4], r2[4];
    int w = t >> 6;
    if ((t & 63) == 0) { r1[w] = s1; r2[w] = s2; }
    __syncthreads();
    if (t == 0) {
        float a = 0.f, c = 0.f;
        for (int i = 0; i < 4; ++i) { a += r1[i]; c += r2[i]; }
        r1[0] = a; r2[0] = c;
    }
    __syncthreads();
    float mean = r1[0] / d;
    float var = r2[0] / d - mean * mean;
    float rstd = rsqrtf(var + 1e-5f);
    for (int i = t; i < d; i += 256) {
        float v = (xr[i] + yr[i] - mean) * rstd * s[i] + b[i];
        xr[i] = v;
        xbr[i] = f2b(v);
    }
}

// ---------------------------------------------------------------------------
// init / concat (write fp32 + bf16 copies)
// ---------------------------------------------------------------------------
__global__ void initx_k(const float* __restrict__ src, float* __restrict__ dst,
                        unsigned short* __restrict__ dstb, int n)
{
    int i = blockIdx.x * blockDim.x + threadIdx.x;
    if (i < n) { float v = src[i]; dst[i] = v; dstb[i] = f2b(v); }
}

__global__ void concat_k(const float* __restrict__ te, const float* __restrict__ ve,
                         float* __restrict__ all, unsigned short* __restrict__ allb)
{
    int i = blockIdx.x * blockDim.x + threadIdx.x;
    if (i >= NTOK * 1536) return;
    int r = i / 1536, c = i % 1536;
    float v = (c < 768) ? te[r * 768 + c] : ve[r * 768 + (c - 768)];
    all[i] = v;
    allb[i] = f2b(v);
}

// ---------------------------------------------------------------------------
// head kernels (fp32)
// ---------------------------------------------------------------------------
__global__ __launch_bounds__(256) void head_ac(
    const float* __restrict__ all, const float* __restrict__ lin_w,
    const float* __restrict__ lin_b, float* __restrict__ a, float* __restrict__ c)
{
    const int i = blockIdx.x, t = threadIdx.x;
    const float* xr = all + (long)i * 1536;
    float s0 = 0.f, s1 = 0.f, s2 = 0.f, s3 = 0.f;
    for (int e = t; e < 1536; e += 256) {
        float v = xr[e];
        s0 += v * lin_w[e];
        s1 += v * lin_w[3072 + e];
        s2 += v * lin_w[1536 + e];
        s3 += v * lin_w[4608 + e];
    }
    for (int off = 32; off; off >>= 1) {
        s0 += __shfl_down(s0, off); s1 += __shfl_down(s1, off);
        s2 += __shfl_down(s2, off); s3 += __shfl_down(s3, off);
    }
    __shared__ float r[4][4];
    int w = t >> 6;
    if ((t & 63) == 0) { r[0][w] = s0; r[1][w] = s1; r[2][w] = s2; r[3][w] = s3; }
    __syncthreads();
    if (t == 0) {
        float t0 = 0.f, t1 = 0.f, t2 = 0.f, t3 = 0.f;
        for (int k = 0; k < 4; ++k) { t0 += r[0][k]; t1 += r[1][k]; t2 += r[2][k]; t3 += r[3][k]; }
        a[i * 2 + 0] = t0 + lin_b[0];
        a[i * 2 + 1] = t1 + lin_b[1];
        c[i * 2 + 0] = t2;
        c[i * 2 + 1] = t3;
    }
}

__global__ __launch_bounds__(384) void head_probs(
    const float* __restrict__ a, const float* __restrict__ c,
    const int* __restrict__ gt, float* __restrict__ probs,
    float* __restrict__ rowsum, float* __restrict__ rowcell)
{
    const int i = blockIdx.x, j = threadIdx.x;
    float l0 = a[i * 2 + 0] + c[j * 2 + 0];
    float l1 = a[i * 2 + 1] + c[j * 2 + 1];
    float m = fmaxf(l0, l1);
    float e0 = __expf(l0 - m), e1 = __expf(l1 - m);
    float inv = 1.f / (e0 + e1);
    float p0 = e0 * inv, p1 = e1 * inv;
    long base = ((long)i * NTOK + j) * 2;
    probs[base] = p0;
    probs[base + 1] = p1;
    float m2 = fmaxf(p0, p1);
    float z = m2 + __logf(__expf(p0 - m2) + __expf(p1 - m2));
    int g = gt[i * NTOK + j];
    float cell = z - (g ? p1 : p0);
    float cs = cell, ps = p1;
    for (int off = 32; off; off >>= 1) { cs += __shfl_down(cs, off); ps += __shfl_down(ps, off); }
    __shared__ float rc[6], rs[6];
    int w = j >> 6;
    if ((j & 63) == 0) { rc[w] = cs; rs[w] = ps; }
    __syncthreads();
    if (j == 0) {
        float csum = 0.f, psum = 0.f;
        for (int k = 0; k < 6; ++k) { csum += rc[k]; psum += rs[k]; }
        rowcell[i] = csum * (1.f / NTOK);
        rowsum[i] = psum;
    }
}

__global__ __launch_bounds__(64) void colsum_k(const float* __restrict__ probs,
                                               float* __restrict__ colsum)
{
    const int j = blockIdx.x, t = threadIdx.x;
    float s = 0.f;
    for (int i = t; i < NTOK; i += 64)
        s += probs[((long)i * NTOK + j) * 2 + 1];
    for (int off = 32; off; off >>= 1) s += __shfl_down(s, off);
    if (t == 0) colsum[j] = s;
}

__global__ __launch_bounds__(384) void finalize_k(
    const float* __restrict__ rowcell, const float* __restrict__ rowsum,
    const float* __restrict__ colsum, float* __restrict__ out)
{
    const int t = threadIdx.x;
    float cls = rowcell[t];
    float ee = (t < NTOK - 1) ? fabsf(rowsum[t] + colsum[t] - 1.f) : 0.f;
    for (int off = 32; off; off >>= 1) { cls += __shfl_down(cls, off); ee += __shfl_down(ee, off); }
    __shared__ float rc[6], re[6];
    int w = t >> 6;
    if ((t & 63) == 0) { rc[w] = cls; re[w] = ee; }
    __syncthreads();
    if (t == 0) {
        float a = 0.f, b = 0.f;
        for (int k = 0; k < 6; ++k) { a += rc[k]; b += re[k]; }
        out[NTOK * NTOK * 2 + 0] = a;
        out[NTOK * NTOK * 2 + 1] = b;
    }
}

// ---------------------------------------------------------------------------
// host-side encoder driver
// ---------------------------------------------------------------------------
static void run_encoder(float* x, unsigned short* xb, int d,
                        const float* qkv_w, const float* qkv_b,
                        const float* out_w, const float* out_b,
                        const float* ln1_s, const float* ln1_b,
                        const float* ff1_w, const float* ff1_b,
                        const float* ff2_w, const float* ff2_b,
                        const float* ln2_s, const float* ln2_b,
                        unsigned short* qkvb, unsigned short* vtb,
                        unsigned short* ob, unsigned short* t1b, float* t2,
                        hipStream_t stream)
{
    const int dq = 3 * d;
    const int hd = d / HEADS;
    const float scale = 1.0f / sqrtf((float)hd);
    for (int l = 0; l < 2; ++l) {
        // qkv = x @ Wqkv^T + b (bf16 out; V block written transposed to vtb)
        gemm_wf32<<<dim3(dq / 128, 3), 256, 0, stream>>>(
            xb, qkv_w + (long)l * dq * d, qkv_b + l * dq, qkvb,
            d, d, dq, 0, 1, vtb, 2 * d);
        // fused attention -> ob
        if (hd == 192)
            attn_fused<192><<<dim3(NTOK / 64, HEADS), 256, 0, stream>>>(
                qkvb, vtb, ob, scale);
        else
            attn_fused<384><<<dim3(NTOK / 64, HEADS), 256, 0, stream>>>(
                qkvb, vtb, ob, scale);
        // out-proj (fp32 out) + LN
        gemm_wf32<<<dim3(d / 128, 3), 256, 0, stream>>>(
            ob, out_w + (long)l * d * d, out_b + l * d, t2,
            d, d, d, 0, 0, nullptr, 0);
        add_ln<<<NTOK, 256, 0, stream>>>(x, xb, t2, ln1_s + l * d, ln1_b + l * d, d);
        // ff1 (relu, bf16 out), ff2 (fp32 out) + LN
        gemm_wf32<<<dim3(2048 / 128, 3), 256, 0, stream>>>(
            xb, ff1_w + (long)l * 2048 * d, ff1_b + l * 2048, t1b,
            d, d, 2048, 1, 1, nullptr, 0);
        gemm_wf32<<<dim3(d / 128, 3), 256, 0, stream>>>(
            t1b, ff2_w + (long)l * d * 2048, ff2_b + l * d, t2,
            2048, 2048, d, 0, 0, nullptr, 0);
        add_ln<<<NTOK, 256, 0, stream>>>(x, xb, t2, ln2_s + l * d, ln2_b + l * d, d);
    }
}

extern "C" void kernel_launch(void* const* d_in, const int* in_sizes, int n_in,
                              void* d_out, int out_size, void* d_ws, size_t ws_size,
                              hipStream_t stream)
{
    const float* text_emb   = (const float*)d_in[0];
    const float* vision_emb = (const float*)d_in[1];
    const int*   gt         = (const int*)  d_in[2];
    const float* t_qkv_w = (const float*)d_in[3];
    const float* t_qkv_b = (const float*)d_in[4];
    const float* t_out_w = (const float*)d_in[5];
    const float* t_out_b = (const float*)d_in[6];
    const float* t_ln1_s = (const float*)d_in[7];
    const float* t_ln1_b = (const float*)d_in[8];
    const float* t_ff1_w = (const float*)d_in[9];
    const float* t_ff1_b = (const float*)d_in[10];
    const float* t_ff2_w = (const float*)d_in[11];
    const float* t_ff2_b = (const float*)d_in[12];
    const float* t_ln2_s = (const float*)d_in[13];
    const float* t_ln2_b = (const float*)d_in[14];
    const float* c_qkv_w = (const float*)d_in[15];
    const float* c_qkv_b = (const float*)d_in[16];
    const float* c_out_w = (const float*)d_in[17];
    const float* c_out_b = (const float*)d_in[18];
    const float* c_ln1_s = (const float*)d_in[19];
    const float* c_ln1_b = (const float*)d_in[20];
    const float* c_ff1_w = (const float*)d_in[21];
    const float* c_ff1_b = (const float*)d_in[22];
    const float* c_ff2_w = (const float*)d_in[23];
    const float* c_ff2_b = (const float*)d_in[24];
    const float* c_ln2_s = (const float*)d_in[25];
    const float* c_ln2_b = (const float*)d_in[26];
    const float* lin_w   = (const float*)d_in[27];
    const float* lin_b   = (const float*)d_in[28];
    float* out = (float*)d_out;

    // ---- workspace layout ----
    float* ws = (float*)d_ws;
    float* xt      = ws;                 // 384*768
    float* all     = xt + 294912;        // 384*1536
    float* t2      = all + 589824;       // 384*1536 (max)
    float* abuf    = t2 + 589824;        // 384*2
    float* cbuf    = abuf + 768;
    float* rowsum  = cbuf + 768;
    float* rowcell = rowsum + 384;
    float* colsum  = rowcell + 384;      // -> fp32 total 1477248
    unsigned short* ub = (unsigned short*)(ws + 1477248);
    unsigned short* xtb   = ub;                  // 294912
    unsigned short* allb  = xtb + 294912;        // 589824
    unsigned short* qkvb  = allb + 589824;       // 384*4608
    unsigned short* vtb   = qkvb + 1769472;      // 1536*384 (max)
    unsigned short* ob    = vtb + 589824;        // 589824
    unsigned short* t1b   = ob + 589824;         // 384*2048

    // ---- text encoder (d = 768) ----
    initx_k<<<(294912 + 255) / 256, 256, 0, stream>>>(text_emb, xt, xtb, 294912);
    run_encoder(xt, xtb, 768,
                t_qkv_w, t_qkv_b, t_out_w, t_out_b, t_ln1_s, t_ln1_b,
                t_ff1_w, t_ff1_b, t_ff2_w, t_ff2_b, t_ln2_s, t_ln2_b,
                qkvb, vtb, ob, t1b, t2, stream);

    // ---- concat -> combined encoder (d = 1536) ----
    concat_k<<<(589824 + 255) / 256, 256, 0, stream>>>(xt, vision_emb, all, allb);
    run_encoder(all, allb, 1536,
                c_qkv_w, c_qkv_b, c_out_w, c_out_b, c_ln1_s, c_ln1_b,
                c_ff1_w, c_ff1_b, c_ff2_w, c_ff2_b, c_ln2_s, c_ln2_b,
                qkvb, vtb, ob, t1b, t2, stream);

    // ---- head ----
    head_ac<<<NTOK, 256, 0, stream>>>(all, lin_w, lin_b, abuf, cbuf);
    head_probs<<<NTOK, 384, 0, stream>>>(abuf, cbuf, gt, out, rowsum, rowcell);
    colsum_k<<<NTOK, 64, 0, stream>>>(out, colsum);
    finalize_k<<<1, 384, 0, stream>>>(rowcell, rowsum, colsum, out);
}

// Round 4
// 1041.273 us; speedup vs baseline: 1.8089x; 1.8089x over previous
//
#include <hip/hip_runtime.h>
#include <hip/hip_bf16.h>
#include <math.h>

#define NTOK 384
#define HEADS 4

typedef __attribute__((ext_vector_type(8))) short bf16x8;
typedef __attribute__((ext_vector_type(4))) float f32x4;

__device__ __forceinline__ unsigned short f2b(float f) {
    union { float f; unsigned int u; } v; v.f = f;
    unsigned int r = (v.u + 0x7fff + ((v.u >> 16) & 1)) >> 16;  // RNE
    return (unsigned short)r;
}

// async 16B global -> LDS (wave-uniform LDS base + lane*16)
__device__ __forceinline__ void g2l16(const void* g, void* l) {
    __builtin_amdgcn_global_load_lds(
        (const __attribute__((address_space(1))) unsigned int*)g,
        (__attribute__((address_space(3))) unsigned int*)l, 16, 0, 0);
}

// ---------------------------------------------------------------------------
// m97-style MFMA bf16 GEMM: C = A(384xK) @ B^T (B NxK) + bias, opt relu,
// fp32/bf16 out, optional transposed write (V block) for cols >= dv2.
// Block 256 thr (2x2 waves), tile 128x128, BK=32, double-buffered LDS staged
// via global_load_lds. LDS tile layout: row-major 64B rows, 16B chunks
// rotated by (row>>1)&3 so ds_read_b128 fragment reads are conflict-free.
// ---------------------------------------------------------------------------
__device__ __forceinline__ void stage_tile(
    const unsigned short* __restrict__ gbase, int row0, int k0, int K,
    char* lds_region, int wid, int lane)
{
    #pragma unroll
    for (int j = 0; j < 2; ++j) {
        int c = j * 256 + wid * 64 + lane;          // chunk 0..511
        int row = c >> 2, p = c & 3;
        int kc = (p - (row >> 1)) & 3;              // global 16B chunk for slot p
        const unsigned short* g = gbase + (long)(row0 + row) * K + k0 + kc * 8;
        char* l = lds_region + (j * 256 + wid * 64) * 16;  // wave-uniform
        g2l16(g, l);
    }
}

__global__ __launch_bounds__(256, 2) void gemm_bf16(
    const unsigned short* __restrict__ A, const unsigned short* __restrict__ B,
    const float* __restrict__ bias, void* __restrict__ Cv,
    int K, int ldc, int relu, int out_bf16,
    unsigned short* __restrict__ vt, int dv2)
{
    __shared__ char smem[2 * 16384];   // [buf][A 8KB | B 8KB]
    const int t = threadIdx.x, lane = t & 63, wid = t >> 6;
    const int wm = wid >> 1, wn = wid & 1;
    const int r16 = lane & 15, quad = lane >> 4;
    const int row0 = blockIdx.y * 128;
    const int col0 = blockIdx.x * 128;

    f32x4 acc[4][4] = {};

    stage_tile(A, row0, 0, K, smem, wid, lane);
    stage_tile(B, col0, 0, K, smem + 8192, wid, lane);
    int buf = 0;

    for (int k0 = 0; k0 < K; k0 += 32) {
        __syncthreads();                 // drains staging (vmcnt) + prior readers
        if (k0 + 32 < K) {
            char* nb = smem + (buf ^ 1) * 16384;
            stage_tile(A, row0, k0 + 32, K, nb, wid, lane);
            stage_tile(B, col0, k0 + 32, K, nb + 8192, wid, lane);
        }
        const char* cb = smem + buf * 16384;
        bf16x8 af[4], bfv[4];
        #pragma unroll
        for (int rt = 0; rt < 4; ++rt) {
            int row = wm * 64 + rt * 16 + r16;
            int p = (quad + (row >> 1)) & 3;
            af[rt] = *reinterpret_cast<const bf16x8*>(cb + row * 64 + p * 16);
        }
        #pragma unroll
        for (int ct = 0; ct < 4; ++ct) {
            int col = wn * 64 + ct * 16 + r16;
            int p = (quad + (col >> 1)) & 3;
            bfv[ct] = *reinterpret_cast<const bf16x8*>(cb + 8192 + col * 64 + p * 16);
        }
        #pragma unroll
        for (int rt = 0; rt < 4; ++rt)
            #pragma unroll
            for (int ct = 0; ct < 4; ++ct)
                acc[rt][ct] = __builtin_amdgcn_mfma_f32_16x16x32_bf16(
                    af[rt], bfv[ct], acc[rt][ct], 0, 0, 0);
        buf ^= 1;
    }

    float* Cf = (float*)Cv;
    unsigned short* Cb = (unsigned short*)Cv;
    const int wcol0 = col0 + wn * 64;
    const int vwrite = (vt != nullptr) && (wcol0 >= dv2);
    #pragma unroll
    for (int rt = 0; rt < 4; ++rt) {
        #pragma unroll
        for (int ct = 0; ct < 4; ++ct) {
            f32x4 v = acc[rt][ct];
            int col = wcol0 + ct * 16 + r16;
            float bi = bias ? bias[col] : 0.f;
            #pragma unroll
            for (int i = 0; i < 4; ++i) {
                v[i] += bi;
                if (relu) v[i] = fmaxf(v[i], 0.f);
            }
            int rbase = row0 + wm * 64 + rt * 16 + quad * 4;
            if (vwrite) {
                ushort4 p;
                p.x = f2b(v[0]); p.y = f2b(v[1]); p.z = f2b(v[2]); p.w = f2b(v[3]);
                *reinterpret_cast<ushort4*>(vt + (long)(col - dv2) * NTOK + rbase) = p;
            } else if (out_bf16) {
                #pragma unroll
                for (int i = 0; i < 4; ++i)
                    Cb[(long)(rbase + i) * ldc + col] = f2b(v[i]);
            } else {
                #pragma unroll
                for (int i = 0; i < 4; ++i)
                    Cf[(long)(rbase + i) * ldc + col] = v[i];
            }
        }
    }
}

// ---------------------------------------------------------------------------
// Fused fp32 -> bf16 conversion of all 8 weight tensors.
// ---------------------------------------------------------------------------
#define WO0 0u
#define WO1 3538944u
#define WO2 4718592u
#define WO3 7864320u
#define WO4 11010048u
#define WO5 25165824u
#define WO6 29884416u
#define WO7 36175872u
#define WTOT 42467328u

__global__ __launch_bounds__(256) void convert_weights(
    const float* __restrict__ s0, const float* __restrict__ s1,
    const float* __restrict__ s2, const float* __restrict__ s3,
    const float* __restrict__ s4, const float* __restrict__ s5,
    const float* __restrict__ s6, const float* __restrict__ s7,
    unsigned short* __restrict__ dst)
{
    unsigned int e = (blockIdx.x * 256u + threadIdx.x) * 4u;
    if (e >= WTOT) return;
    const float* src; unsigned int local;
    if      (e < WO1) { src = s0; local = e - WO0; }
    else if (e < WO2) { src = s1; local = e - WO1; }
    else if (e < WO3) { src = s2; local = e - WO2; }
    else if (e < WO4) { src = s3; local = e - WO3; }
    else if (e < WO5) { src = s4; local = e - WO4; }
    else if (e < WO6) { src = s5; local = e - WO5; }
    else if (e < WO7) { src = s6; local = e - WO6; }
    else              { src = s7; local = e - WO7; }
    float4 v = *reinterpret_cast<const float4*>(src + local);
    ushort4 o;
    o.x = f2b(v.x); o.y = f2b(v.y); o.z = f2b(v.z); o.w = f2b(v.w);
    *reinterpret_cast<ushort4*>(dst + e) = o;
}

// ---------------------------------------------------------------------------
// Fused attention: one wave per 16 q-rows per head. grid (24, HEADS), 64 thr.
// S = Q@K^T (in-reg), softmax, P via LDS (C-layout -> A-layout), O = P@V^T.
// ---------------------------------------------------------------------------
template <int HD>
__global__ __launch_bounds__(64, 2) void attn_fused(
    const unsigned short* __restrict__ qkv, const unsigned short* __restrict__ vt,
    unsigned short* __restrict__ o, float scale)
{
    constexpr int D = HD * HEADS;
    constexpr int LDQ = 3 * D;
    __shared__ unsigned short plds[16 * NTOK];

    const int lane = threadIdx.x;
    const int r16 = lane & 15, quad = lane >> 4;
    const int qbase = blockIdx.x * 16;
    const int h = blockIdx.y;

    // ---- phase 1: S = Q @ K^T  (16 x 384) ----
    f32x4 s[24] = {};
    const unsigned short* Qp = qkv + (long)(qbase + r16) * LDQ + h * HD + quad * 8;
    const unsigned short* Kp = qkv + D + h * HD + quad * 8;
    for (int k0 = 0; k0 < HD; k0 += 32) {
        bf16x8 qa = *reinterpret_cast<const bf16x8*>(Qp + k0);
        #pragma unroll
        for (int ct = 0; ct < 24; ++ct) {
            bf16x8 kb = *reinterpret_cast<const bf16x8*>(
                Kp + (long)(ct * 16 + r16) * LDQ + k0);
            s[ct] = __builtin_amdgcn_mfma_f32_16x16x32_bf16(qa, kb, s[ct], 0, 0, 0);
        }
    }

    // ---- softmax: row = quad*4+i, cols spread over 16 lanes ----
    float mrow[4] = {-1e30f, -1e30f, -1e30f, -1e30f};
    #pragma unroll
    for (int ct = 0; ct < 24; ++ct)
        #pragma unroll
        for (int i = 0; i < 4; ++i) mrow[i] = fmaxf(mrow[i], s[ct][i]);
    #pragma unroll
    for (int m = 1; m <= 8; m <<= 1)
        #pragma unroll
        for (int i = 0; i < 4; ++i) mrow[i] = fmaxf(mrow[i], __shfl_xor(mrow[i], m));
    float sum[4] = {};
    #pragma unroll
    for (int ct = 0; ct < 24; ++ct)
        #pragma unroll
        for (int i = 0; i < 4; ++i) {
            float e = __expf((s[ct][i] - mrow[i]) * scale);
            s[ct][i] = e; sum[i] += e;
        }
    #pragma unroll
    for (int m = 1; m <= 8; m <<= 1)
        #pragma unroll
        for (int i = 0; i < 4; ++i) sum[i] += __shfl_xor(sum[i], m);
    float inv[4];
    #pragma unroll
    for (int i = 0; i < 4; ++i) inv[i] = 1.f / sum[i];

    #pragma unroll
    for (int ct = 0; ct < 24; ++ct)
        #pragma unroll
        for (int i = 0; i < 4; ++i)
            plds[(quad * 4 + i) * NTOK + ct * 16 + r16] = f2b(s[ct][i] * inv[i]);
    __syncthreads();

    // ---- phase 2: O = P @ V^T ----
    f32x4 oa[HD / 16] = {};
    const unsigned short* Vp = vt + (long)(h * HD + r16) * NTOK + quad * 8;
    for (int k0 = 0; k0 < NTOK; k0 += 32) {
        bf16x8 pa = *reinterpret_cast<const bf16x8*>(
            &plds[r16 * NTOK + k0 + quad * 8]);
        #pragma unroll
        for (int ct = 0; ct < HD / 16; ++ct) {
            bf16x8 vb = *reinterpret_cast<const bf16x8*>(
                Vp + (long)ct * 16 * NTOK + k0);
            oa[ct] = __builtin_amdgcn_mfma_f32_16x16x32_bf16(pa, vb, oa[ct], 0, 0, 0);
        }
    }
    #pragma unroll
    for (int ct = 0; ct < HD / 16; ++ct)
        #pragma unroll
        for (int i = 0; i < 4; ++i)
            o[(long)(qbase + quad * 4 + i) * D + h * HD + ct * 16 + r16] =
                f2b(oa[ct][i]);
}

// ---------------------------------------------------------------------------
// x = LayerNorm(x + y) * s + b  (fp32), also writes bf16 copy xb.
// ---------------------------------------------------------------------------
__global__ __launch_bounds__(256) void add_ln(
    float* __restrict__ x, unsigned short* __restrict__ xb,
    const float* __restrict__ y,
    const float* __restrict__ s, const float* __restrict__ b, int d)
{
    float* xr = x + (long)blockIdx.x * d;
    unsigned short* xbr = xb + (long)blockIdx.x * d;
    const float* yr = y + (long)blockIdx.x * d;
    const int t = threadIdx.x;
    float s1 = 0.f, s2 = 0.f;
    for (int i = t; i < d; i += 256) {
        float v = xr[i] + yr[i];
        s1 += v; s2 += v * v;
    }
    for (int off = 32; off; off >>= 1) { s1 += __shfl_down(s1, off); s2 += __shfl_down(s2, off); }
    __shared__ float r1[4], r2[4];
    int w = t >> 6;
    if ((t & 63) == 0) { r1[w] = s1; r2[w] = s2; }
    __syncthreads();
    if (t == 0) {
        float a = 0.f, c = 0.f;
        for (int i = 0; i < 4; ++i) { a += r1[i]; c += r2[i]; }
        r1[0] = a; r2[0] = c;
    }
    __syncthreads();
    float mean = r1[0] / d;
    float var = r2[0] / d - mean * mean;
    float rstd = rsqrtf(var + 1e-5f);
    for (int i = t; i < d; i += 256) {
        float v = (xr[i] + yr[i] - mean) * rstd * s[i] + b[i];
        xr[i] = v;
        xbr[i] = f2b(v);
    }
}

// ---------------------------------------------------------------------------
// init / concat (write fp32 + bf16 copies)
// ---------------------------------------------------------------------------
__global__ void initx_k(const float* __restrict__ src, float* __restrict__ dst,
                        unsigned short* __restrict__ dstb, int n)
{
    int i = blockIdx.x * blockDim.x + threadIdx.x;
    if (i < n) { float v = src[i]; dst[i] = v; dstb[i] = f2b(v); }
}

__global__ void concat_k(const float* __restrict__ te, const float* __restrict__ ve,
                         float* __restrict__ all, unsigned short* __restrict__ allb)
{
    int i = blockIdx.x * blockDim.x + threadIdx.x;
    if (i >= NTOK * 1536) return;
    int r = i / 1536, c = i % 1536;
    float v = (c < 768) ? te[r * 768 + c] : ve[r * 768 + (c - 768)];
    all[i] = v;
    allb[i] = f2b(v);
}

// ---------------------------------------------------------------------------
// head kernels (fp32)
// ---------------------------------------------------------------------------
__global__ __launch_bounds__(256) void head_ac(
    const float* __restrict__ all, const float* __restrict__ lin_w,
    const float* __restrict__ lin_b, float* __restrict__ a, float* __restrict__ c)
{
    const int i = blockIdx.x, t = threadIdx.x;
    const float* xr = all + (long)i * 1536;
    float s0 = 0.f, s1 = 0.f, s2 = 0.f, s3 = 0.f;
    for (int e = t; e < 1536; e += 256) {
        float v = xr[e];
        s0 += v * lin_w[e];
        s1 += v * lin_w[3072 + e];
        s2 += v * lin_w[1536 + e];
        s3 += v * lin_w[4608 + e];
    }
    for (int off = 32; off; off >>= 1) {
        s0 += __shfl_down(s0, off); s1 += __shfl_down(s1, off);
        s2 += __shfl_down(s2, off); s3 += __shfl_down(s3, off);
    }
    __shared__ float r[4][4];
    int w = t >> 6;
    if ((t & 63) == 0) { r[0][w] = s0; r[1][w] = s1; r[2][w] = s2; r[3][w] = s3; }
    __syncthreads();
    if (t == 0) {
        float t0 = 0.f, t1 = 0.f, t2 = 0.f, t3 = 0.f;
        for (int k = 0; k < 4; ++k) { t0 += r[0][k]; t1 += r[1][k]; t2 += r[2][k]; t3 += r[3][k]; }
        a[i * 2 + 0] = t0 + lin_b[0];
        a[i * 2 + 1] = t1 + lin_b[1];
        c[i * 2 + 0] = t2;
        c[i * 2 + 1] = t3;
    }
}

__global__ __launch_bounds__(384) void head_probs(
    const float* __restrict__ a, const float* __restrict__ c,
    const int* __restrict__ gt, float* __restrict__ probs,
    float* __restrict__ rowsum, float* __restrict__ rowcell)
{
    const int i = blockIdx.x, j = threadIdx.x;
    float l0 = a[i * 2 + 0] + c[j * 2 + 0];
    float l1 = a[i * 2 + 1] + c[j * 2 + 1];
    float m = fmaxf(l0, l1);
    float e0 = __expf(l0 - m), e1 = __expf(l1 - m);
    float inv = 1.f / (e0 + e1);
    float p0 = e0 * inv, p1 = e1 * inv;
    long base = ((long)i * NTOK + j) * 2;
    probs[base] = p0;
    probs[base + 1] = p1;
    float m2 = fmaxf(p0, p1);
    float z = m2 + __logf(__expf(p0 - m2) + __expf(p1 - m2));
    int g = gt[i * NTOK + j];
    float cell = z - (g ? p1 : p0);
    float cs = cell, ps = p1;
    for (int off = 32; off; off >>= 1) { cs += __shfl_down(cs, off); ps += __shfl_down(ps, off); }
    __shared__ float rc[6], rs[6];
    int w = j >> 6;
    if ((j & 63) == 0) { rc[w] = cs; rs[w] = ps; }
    __syncthreads();
    if (j == 0) {
        float csum = 0.f, psum = 0.f;
        for (int k = 0; k < 6; ++k) { csum += rc[k]; psum += rs[k]; }
        rowcell[i] = csum * (1.f / NTOK);
        rowsum[i] = psum;
    }
}

__global__ __launch_bounds__(64) void colsum_k(const float* __restrict__ probs,
                                               float* __restrict__ colsum)
{
    const int j = blockIdx.x, t = threadIdx.x;
    float s = 0.f;
    for (int i = t; i < NTOK; i += 64)
        s += probs[((long)i * NTOK + j) * 2 + 1];
    for (int off = 32; off; off >>= 1) s += __shfl_down(s, off);
    if (t == 0) colsum[j] = s;
}

__global__ __launch_bounds__(384) void finalize_k(
    const float* __restrict__ rowcell, const float* __restrict__ rowsum,
    const float* __restrict__ colsum, float* __restrict__ out)
{
    const int t = threadIdx.x;
    float cls = rowcell[t];
    float ee = (t < NTOK - 1) ? fabsf(rowsum[t] + colsum[t] - 1.f) : 0.f;
    for (int off = 32; off; off >>= 1) { cls += __shfl_down(cls, off); ee += __shfl_down(ee, off); }
    __shared__ float rc[6], re[6];
    int w = t >> 6;
    if ((t & 63) == 0) { rc[w] = cls; re[w] = ee; }
    __syncthreads();
    if (t == 0) {
        float a = 0.f, b = 0.f;
        for (int k = 0; k < 6; ++k) { a += rc[k]; b += re[k]; }
        out[NTOK * NTOK * 2 + 0] = a;
        out[NTOK * NTOK * 2 + 1] = b;
    }
}

// ---------------------------------------------------------------------------
// host-side encoder driver (bf16 weights, LDS-staged MFMA GEMM)
// ---------------------------------------------------------------------------
static void run_encoder(float* x, unsigned short* xb, int d,
                        const unsigned short* wq, const unsigned short* wo,
                        const unsigned short* w1, const unsigned short* w2,
                        const float* qkv_b, const float* out_b,
                        const float* ln1_s, const float* ln1_b,
                        const float* ff1_b, const float* ff2_b,
                        const float* ln2_s, const float* ln2_b,
                        unsigned short* qkvb, unsigned short* vtb,
                        unsigned short* ob, unsigned short* t1b, float* t2,
                        hipStream_t stream)
{
    const int dq = 3 * d;
    const int hd = d / HEADS;
    const float scale = 1.0f / sqrtf((float)hd);
    for (int l = 0; l < 2; ++l) {
        // qkv = x @ Wqkv^T + b (bf16 out; V block written transposed to vtb)
        gemm_bf16<<<dim3(dq / 128, 3), 256, 0, stream>>>(
            xb, wq + (long)l * dq * d, qkv_b + l * dq, qkvb,
            d, dq, 0, 1, vtb, 2 * d);
        // fused attention -> ob
        if (hd == 192)
            attn_fused<192><<<dim3(NTOK / 16, HEADS), 64, 0, stream>>>(
                qkvb, vtb, ob, scale);
        else
            attn_fused<384><<<dim3(NTOK / 16, HEADS), 64, 0, stream>>>(
                qkvb, vtb, ob, scale);
        // out-proj (fp32 out) + LN
        gemm_bf16<<<dim3(d / 128, 3), 256, 0, stream>>>(
            ob, wo + (long)l * d * d, out_b + l * d, t2,
            d, d, 0, 0, nullptr, 0);
        add_ln<<<NTOK, 256, 0, stream>>>(x, xb, t2, ln1_s + l * d, ln1_b + l * d, d);
        // ff1 (relu, bf16 out), ff2 (fp32 out) + LN
        gemm_bf16<<<dim3(2048 / 128, 3), 256, 0, stream>>>(
            xb, w1 + (long)l * 2048 * d, ff1_b + l * 2048, t1b,
            d, 2048, 1, 1, nullptr, 0);
        gemm_bf16<<<dim3(d / 128, 3), 256, 0, stream>>>(
            t1b, w2 + (long)l * d * 2048, ff2_b + l * d, t2,
            2048, d, 0, 0, nullptr, 0);
        add_ln<<<NTOK, 256, 0, stream>>>(x, xb, t2, ln2_s + l * d, ln2_b + l * d, d);
    }
}

extern "C" void kernel_launch(void* const* d_in, const int* in_sizes, int n_in,
                              void* d_out, int out_size, void* d_ws, size_t ws_size,
                              hipStream_t stream)
{
    const float* text_emb   = (const float*)d_in[0];
    const float* vision_emb = (const float*)d_in[1];
    const int*   gt         = (const int*)  d_in[2];
    const float* t_qkv_w = (const float*)d_in[3];
    const float* t_qkv_b = (const float*)d_in[4];
    const float* t_out_w = (const float*)d_in[5];
    const float* t_out_b = (const float*)d_in[6];
    const float* t_ln1_s = (const float*)d_in[7];
    const float* t_ln1_b = (const float*)d_in[8];
    const float* t_ff1_w = (const float*)d_in[9];
    const float* t_ff1_b = (const float*)d_in[10];
    const float* t_ff2_w = (const float*)d_in[11];
    const float* t_ff2_b = (const float*)d_in[12];
    const float* t_ln2_s = (const float*)d_in[13];
    const float* t_ln2_b = (const float*)d_in[14];
    const float* c_qkv_w = (const float*)d_in[15];
    const float* c_qkv_b = (const float*)d_in[16];
    const float* c_out_w = (const float*)d_in[17];
    const float* c_out_b = (const float*)d_in[18];
    const float* c_ln1_s = (const float*)d_in[19];
    const float* c_ln1_b = (const float*)d_in[20];
    const float* c_ff1_w = (const float*)d_in[21];
    const float* c_ff1_b = (const float*)d_in[22];
    const float* c_ff2_w = (const float*)d_in[23];
    const float* c_ff2_b = (const float*)d_in[24];
    const float* c_ln2_s = (const float*)d_in[25];
    const float* c_ln2_b = (const float*)d_in[26];
    const float* lin_w   = (const float*)d_in[27];
    const float* lin_b   = (const float*)d_in[28];
    float* out = (float*)d_out;

    // ---- workspace layout ----
    float* ws = (float*)d_ws;
    float* xt      = ws;                 // 384*768
    float* all     = xt + 294912;        // 384*1536
    float* t2      = all + 589824;       // 384*1536 (max)
    float* abuf    = t2 + 589824;
    float* cbuf    = abuf + 768;
    float* rowsum  = cbuf + 768;
    float* rowcell = rowsum + 384;
    float* colsum  = rowcell + 384;      // fp32 total 1477248
    unsigned short* ub = (unsigned short*)(ws + 1477248);
    unsigned short* xtb   = ub;                  // 294912
    unsigned short* allb  = xtb + 294912;        // 589824
    unsigned short* qkvb  = allb + 589824;       // 384*4608
    unsigned short* vtb   = qkvb + 1769472;      // 1536*384 (max)
    unsigned short* ob    = vtb + 589824;        // 589824
    unsigned short* t1b   = ob + 589824;         // 384*2048
    unsigned short* wb    = t1b + 786432;        // 42467328 bf16 weights

    // ---- weight conversion (one fused launch) ----
    convert_weights<<<(WTOT / 4 + 255) / 256, 256, 0, stream>>>(
        t_qkv_w, t_out_w, t_ff1_w, t_ff2_w,
        c_qkv_w, c_out_w, c_ff1_w, c_ff2_w, wb);

    // ---- text encoder (d = 768) ----
    initx_k<<<(294912 + 255) / 256, 256, 0, stream>>>(text_emb, xt, xtb, 294912);
    run_encoder(xt, xtb, 768,
                wb + WO0, wb + WO1, wb + WO2, wb + WO3,
                t_qkv_b, t_out_b, t_ln1_s, t_ln1_b,
                t_ff1_b, t_ff2_b, t_ln2_s, t_ln2_b,
                qkvb, vtb, ob, t1b, t2, stream);

    // ---- concat -> combined encoder (d = 1536) ----
    concat_k<<<(589824 + 255) / 256, 256, 0, stream>>>(xt, vision_emb, all, allb);
    run_encoder(all, allb, 1536,
                wb + WO4, wb + WO5, wb + WO6, wb + WO7,
                c_qkv_b, c_out_b, c_ln1_s, c_ln1_b,
                c_ff1_b, c_ff2_b, c_ln2_s, c_ln2_b,
                qkvb, vtb, ob, t1b, t2, stream);

    // ---- head ----
    head_ac<<<NTOK, 256, 0, stream>>>(all, lin_w, lin_b, abuf, cbuf);
    head_probs<<<NTOK, 384, 0, stream>>>(abuf, cbuf, gt, out, rowsum, rowcell);
    colsum_k<<<NTOK, 64, 0, stream>>>(out, colsum);
    finalize_k<<<1, 384, 0, stream>>>(rowcell, rowsum, colsum, out);
}

// Round 5
// 853.260 us; speedup vs baseline: 2.2075x; 1.2203x over previous
//
#include <hip/hip_runtime.h>
#include <hip/hip_bf16.h>
#include <math.h>

#define NTOK 384
#define HEADS 4

typedef __attribute__((ext_vector_type(8))) short bf16x8;
typedef __attribute__((ext_vector_type(4))) float f32x4;

__device__ __forceinline__ unsigned short f2b(float f) {
    union { float f; unsigned int u; } v; v.f = f;
    unsigned int r = (v.u + 0x7fff + ((v.u >> 16) & 1)) >> 16;  // RNE
    return (unsigned short)r;
}

// async 16B global -> LDS (wave-uniform LDS base + lane*16)
__device__ __forceinline__ void g2l16(const void* g, void* l) {
    __builtin_amdgcn_global_load_lds(
        (const __attribute__((address_space(1))) unsigned int*)g,
        (__attribute__((address_space(3))) unsigned int*)l, 16, 0, 0);
}

// ---------------------------------------------------------------------------
// m97-style MFMA bf16 GEMM: C = A(384xK) @ B^T (B NxK) + bias, opt relu,
// fp32/bf16 out, optional transposed write (V block) for cols >= dv2.
// Block 256 thr (2x2 waves), tile 128x128, BK=32, double-buffered LDS staged
// via global_load_lds. LDS rows 64B, 16B chunks rotated by (row>>1)&3.
// ---------------------------------------------------------------------------
__device__ __forceinline__ void stage_tile(
    const unsigned short* __restrict__ gbase, int row0, int k0, int K,
    char* lds_region, int wid, int lane)
{
    #pragma unroll
    for (int j = 0; j < 2; ++j) {
        int c = j * 256 + wid * 64 + lane;          // chunk 0..511
        int row = c >> 2, p = c & 3;
        int kc = (p - (row >> 1)) & 3;              // global 16B chunk for slot p
        const unsigned short* g = gbase + (long)(row0 + row) * K + k0 + kc * 8;
        char* l = lds_region + (j * 256 + wid * 64) * 16;  // wave-uniform
        g2l16(g, l);
    }
}

__global__ __launch_bounds__(256, 2) void gemm_bf16(
    const unsigned short* __restrict__ A, const unsigned short* __restrict__ B,
    const float* __restrict__ bias, void* __restrict__ Cv,
    int K, int ldc, int relu, int out_bf16,
    unsigned short* __restrict__ vt, int dv2)
{
    __shared__ char smem[2 * 16384];   // [buf][A 8KB | B 8KB]
    const int t = threadIdx.x, lane = t & 63, wid = t >> 6;
    const int wm = wid >> 1, wn = wid & 1;
    const int r16 = lane & 15, quad = lane >> 4;
    const int row0 = blockIdx.y * 128;
    const int col0 = blockIdx.x * 128;

    f32x4 acc[4][4] = {};

    stage_tile(A, row0, 0, K, smem, wid, lane);
    stage_tile(B, col0, 0, K, smem + 8192, wid, lane);
    int buf = 0;

    for (int k0 = 0; k0 < K; k0 += 32) {
        __syncthreads();
        if (k0 + 32 < K) {
            char* nb = smem + (buf ^ 1) * 16384;
            stage_tile(A, row0, k0 + 32, K, nb, wid, lane);
            stage_tile(B, col0, k0 + 32, K, nb + 8192, wid, lane);
        }
        const char* cb = smem + buf * 16384;
        bf16x8 af[4], bfv[4];
        #pragma unroll
        for (int rt = 0; rt < 4; ++rt) {
            int row = wm * 64 + rt * 16 + r16;
            int p = (quad + (row >> 1)) & 3;
            af[rt] = *reinterpret_cast<const bf16x8*>(cb + row * 64 + p * 16);
        }
        #pragma unroll
        for (int ct = 0; ct < 4; ++ct) {
            int col = wn * 64 + ct * 16 + r16;
            int p = (quad + (col >> 1)) & 3;
            bfv[ct] = *reinterpret_cast<const bf16x8*>(cb + 8192 + col * 64 + p * 16);
        }
        #pragma unroll
        for (int rt = 0; rt < 4; ++rt)
            #pragma unroll
            for (int ct = 0; ct < 4; ++ct)
                acc[rt][ct] = __builtin_amdgcn_mfma_f32_16x16x32_bf16(
                    af[rt], bfv[ct], acc[rt][ct], 0, 0, 0);
        buf ^= 1;
    }

    float* Cf = (float*)Cv;
    unsigned short* Cb = (unsigned short*)Cv;
    const int wcol0 = col0 + wn * 64;
    const int vwrite = (vt != nullptr) && (wcol0 >= dv2);
    #pragma unroll
    for (int rt = 0; rt < 4; ++rt) {
        #pragma unroll
        for (int ct = 0; ct < 4; ++ct) {
            f32x4 v = acc[rt][ct];
            int col = wcol0 + ct * 16 + r16;
            float bi = bias ? bias[col] : 0.f;
            #pragma unroll
            for (int i = 0; i < 4; ++i) {
                v[i] += bi;
                if (relu) v[i] = fmaxf(v[i], 0.f);
            }
            int rbase = row0 + wm * 64 + rt * 16 + quad * 4;
            if (vwrite) {
                ushort4 p;
                p.x = f2b(v[0]); p.y = f2b(v[1]); p.z = f2b(v[2]); p.w = f2b(v[3]);
                *reinterpret_cast<ushort4*>(vt + (long)(col - dv2) * NTOK + rbase) = p;
            } else if (out_bf16) {
                #pragma unroll
                for (int i = 0; i < 4; ++i)
                    Cb[(long)(rbase + i) * ldc + col] = f2b(v[i]);
            } else {
                #pragma unroll
                for (int i = 0; i < 4; ++i)
                    Cf[(long)(rbase + i) * ldc + col] = v[i];
            }
        }
    }
}

// ---------------------------------------------------------------------------
// Fused fp32 -> bf16 conversion of all 8 weight tensors.
// ---------------------------------------------------------------------------
#define WO0 0u
#define WO1 3538944u
#define WO2 4718592u
#define WO3 7864320u
#define WO4 11010048u
#define WO5 25165824u
#define WO6 29884416u
#define WO7 36175872u
#define WTOT 42467328u

__global__ __launch_bounds__(256) void convert_weights(
    const float* __restrict__ s0, const float* __restrict__ s1,
    const float* __restrict__ s2, const float* __restrict__ s3,
    const float* __restrict__ s4, const float* __restrict__ s5,
    const float* __restrict__ s6, const float* __restrict__ s7,
    unsigned short* __restrict__ dst)
{
    unsigned int e = (blockIdx.x * 256u + threadIdx.x) * 4u;
    if (e >= WTOT) return;
    const float* src; unsigned int local;
    if      (e < WO1) { src = s0; local = e - WO0; }
    else if (e < WO2) { src = s1; local = e - WO1; }
    else if (e < WO3) { src = s2; local = e - WO2; }
    else if (e < WO4) { src = s3; local = e - WO3; }
    else if (e < WO5) { src = s4; local = e - WO4; }
    else if (e < WO6) { src = s5; local = e - WO5; }
    else if (e < WO7) { src = s6; local = e - WO6; }
    else              { src = s7; local = e - WO7; }
    float4 v = *reinterpret_cast<const float4*>(src + local);
    ushort4 o;
    o.x = f2b(v.x); o.y = f2b(v.y); o.z = f2b(v.z); o.w = f2b(v.w);
    *reinterpret_cast<ushort4*>(dst + e) = o;
}

// ---------------------------------------------------------------------------
// Fused attention v3: grid (NTOK/64, HEADS), block 256 = 4 waves.
// Wave w owns q rows [qt*64 + w*16, +16). K and V^T staged through
// double-buffered 64x32 LDS tiles (gemm-identical XOR layout, coalesced
// global_load_lds). P round-trips through padded LDS (C->A layout).
// ---------------------------------------------------------------------------
__device__ __forceinline__ void stage64x32(
    const unsigned short* __restrict__ g, int ld,
    unsigned short* __restrict__ region, int t)
{
    int row = t >> 2, p = t & 3;
    int kc = (p - (row >> 1)) & 3;
    g2l16(g + (long)row * ld + kc * 8, (char*)region + t * 16);
}

template <int HD>
__global__ __launch_bounds__(256, 1) void attn_fused(
    const unsigned short* __restrict__ qkv, const unsigned short* __restrict__ vt,
    unsigned short* __restrict__ o, float scale)
{
    constexpr int D = HD * HEADS;
    constexpr int LDQ = 3 * D;
    constexpr int PP = 392;                       // P row pitch (elems)
    __shared__ unsigned short kbuf[2][64 * 32];   // 2 x 4KB staging
    __shared__ unsigned short plds[4][16 * PP];   // ~49KB

    const int t = threadIdx.x, lane = t & 63, w = t >> 6;
    const int r16 = lane & 15, quad = lane >> 4;
    const int qbase = blockIdx.x * 64 + w * 16;
    const int h = blockIdx.y;

    // preload Q fragments (reused across all kv-tiles)
    const unsigned short* Qp = qkv + (long)(qbase + r16) * LDQ + h * HD + quad * 8;
    bf16x8 qf[HD / 32];
    #pragma unroll
    for (int kk = 0; kk < HD / 32; ++kk)
        qf[kk] = *reinterpret_cast<const bf16x8*>(Qp + kk * 32);

    // ---- phase 1: S = Q @ K^T, K staged in LDS ----
    const unsigned short* Kbase = qkv + D + h * HD;
    f32x4 s[24] = {};
    int buf = 0;
    stage64x32(Kbase, LDQ, kbuf[0], t);
    for (int kv0 = 0; kv0 < NTOK; kv0 += 64) {
        for (int k0 = 0; k0 < HD; k0 += 32) {
            __syncthreads();
            int nkv = kv0, nk = k0 + 32;
            if (nk == HD) { nkv += 64; nk = 0; }
            if (nkv < NTOK)
                stage64x32(Kbase + (long)nkv * LDQ + nk, LDQ, kbuf[buf ^ 1], t);
            bf16x8 qa = qf[k0 / 32];
            #pragma unroll
            for (int j = 0; j < 4; ++j) {
                int r = j * 16 + r16;
                int p = (quad + (r >> 1)) & 3;
                bf16x8 kb = *reinterpret_cast<const bf16x8*>(
                    &kbuf[buf][r * 32 + p * 8]);
                s[kv0 / 16 + j] = __builtin_amdgcn_mfma_f32_16x16x32_bf16(
                    qa, kb, s[kv0 / 16 + j], 0, 0, 0);
            }
            buf ^= 1;
        }
    }

    // prefetch first V^T tile (into the buffer not read by the last iteration)
    const unsigned short* Vbase = vt + (long)h * HD * NTOK;
    stage64x32(Vbase, NTOK, kbuf[buf], t);

    // ---- softmax: row = quad*4+i, cols spread over 16 lanes ----
    float mrow[4] = {-1e30f, -1e30f, -1e30f, -1e30f};
    #pragma unroll
    for (int ct = 0; ct < 24; ++ct)
        #pragma unroll
        for (int i = 0; i < 4; ++i) mrow[i] = fmaxf(mrow[i], s[ct][i]);
    #pragma unroll
    for (int m = 1; m <= 8; m <<= 1)
        #pragma unroll
        for (int i = 0; i < 4; ++i) mrow[i] = fmaxf(mrow[i], __shfl_xor(mrow[i], m));
    float sum[4] = {};
    #pragma unroll
    for (int ct = 0; ct < 24; ++ct)
        #pragma unroll
        for (int i = 0; i < 4; ++i) {
            float e = __expf((s[ct][i] - mrow[i]) * scale);
            s[ct][i] = e; sum[i] += e;
        }
    #pragma unroll
    for (int m = 1; m <= 8; m <<= 1)
        #pragma unroll
        for (int i = 0; i < 4; ++i) sum[i] += __shfl_xor(sum[i], m);
    float inv[4];
    #pragma unroll
    for (int i = 0; i < 4; ++i) inv[i] = 1.f / sum[i];

    // P -> LDS (per-wave region, padded pitch; C-layout -> A-layout)
    #pragma unroll
    for (int ct = 0; ct < 24; ++ct)
        #pragma unroll
        for (int i = 0; i < 4; ++i)
            plds[w][(quad * 4 + i) * PP + ct * 16 + r16] = f2b(s[ct][i] * inv[i]);

    // ---- phase 2: O = P @ V^T, V^T staged in LDS ----
    f32x4 oa[HD / 16] = {};
    for (int hd0 = 0; hd0 < HD; hd0 += 64) {
        for (int k0 = 0; k0 < NTOK; k0 += 32) {
            __syncthreads();
            int nhd = hd0, nk = k0 + 32;
            if (nk == NTOK) { nhd += 64; nk = 0; }
            if (nhd < HD)
                stage64x32(Vbase + (long)nhd * NTOK + nk, NTOK, kbuf[buf ^ 1], t);
            bf16x8 pa = *reinterpret_cast<const bf16x8*>(
                &plds[w][r16 * PP + k0 + quad * 8]);
            #pragma unroll
            for (int j = 0; j < 4; ++j) {
                int r = j * 16 + r16;
                int p = (quad + (r >> 1)) & 3;
                bf16x8 vb = *reinterpret_cast<const bf16x8*>(
                    &kbuf[buf][r * 32 + p * 8]);
                oa[hd0 / 16 + j] = __builtin_amdgcn_mfma_f32_16x16x32_bf16(
                    pa, vb, oa[hd0 / 16 + j], 0, 0, 0);
            }
            buf ^= 1;
        }
    }

    #pragma unroll
    for (int ct = 0; ct < HD / 16; ++ct)
        #pragma unroll
        for (int i = 0; i < 4; ++i)
            o[(long)(qbase + quad * 4 + i) * D + h * HD + ct * 16 + r16] =
                f2b(oa[ct][i]);
}

// ---------------------------------------------------------------------------
// x = LayerNorm(x + y) * s + b  (fp32), also writes bf16 copy xb.
// ---------------------------------------------------------------------------
__global__ __launch_bounds__(256) void add_ln(
    float* __restrict__ x, unsigned short* __restrict__ xb,
    const float* __restrict__ y,
    const float* __restrict__ s, const float* __restrict__ b, int d)
{
    float* xr = x + (long)blockIdx.x * d;
    unsigned short* xbr = xb + (long)blockIdx.x * d;
    const float* yr = y + (long)blockIdx.x * d;
    const int t = threadIdx.x;
    float s1 = 0.f, s2 = 0.f;
    for (int i = t; i < d; i += 256) {
        float v = xr[i] + yr[i];
        s1 += v; s2 += v * v;
    }
    for (int off = 32; off; off >>= 1) { s1 += __shfl_down(s1, off); s2 += __shfl_down(s2, off); }
    __shared__ float r1[4], r2[4];
    int w = t >> 6;
    if ((t & 63) == 0) { r1[w] = s1; r2[w] = s2; }
    __syncthreads();
    if (t == 0) {
        float a = 0.f, c = 0.f;
        for (int i = 0; i < 4; ++i) { a += r1[i]; c += r2[i]; }
        r1[0] = a; r2[0] = c;
    }
    __syncthreads();
    float mean = r1[0] / d;
    float var = r2[0] / d - mean * mean;
    float rstd = rsqrtf(var + 1e-5f);
    for (int i = t; i < d; i += 256) {
        float v = (xr[i] + yr[i] - mean) * rstd * s[i] + b[i];
        xr[i] = v;
        xbr[i] = f2b(v);
    }
}

// ---------------------------------------------------------------------------
// init / concat (write fp32 + bf16 copies)
// ---------------------------------------------------------------------------
__global__ void initx_k(const float* __restrict__ src, float* __restrict__ dst,
                        unsigned short* __restrict__ dstb, int n)
{
    int i = blockIdx.x * blockDim.x + threadIdx.x;
    if (i < n) { float v = src[i]; dst[i] = v; dstb[i] = f2b(v); }
}

__global__ void concat_k(const float* __restrict__ te, const float* __restrict__ ve,
                         float* __restrict__ all, unsigned short* __restrict__ allb)
{
    int i = blockIdx.x * blockDim.x + threadIdx.x;
    if (i >= NTOK * 1536) return;
    int r = i / 1536, c = i % 1536;
    float v = (c < 768) ? te[r * 768 + c] : ve[r * 768 + (c - 768)];
    all[i] = v;
    allb[i] = f2b(v);
}

// ---------------------------------------------------------------------------
// head kernels (fp32)
// ---------------------------------------------------------------------------
__global__ __launch_bounds__(256) void head_ac(
    const float* __restrict__ all, const float* __restrict__ lin_w,
    const float* __restrict__ lin_b, float* __restrict__ a, float* __restrict__ c)
{
    const int i = blockIdx.x, t = threadIdx.x;
    const float* xr = all + (long)i * 1536;
    float s0 = 0.f, s1 = 0.f, s2 = 0.f, s3 = 0.f;
    for (int e = t; e < 1536; e += 256) {
        float v = xr[e];
        s0 += v * lin_w[e];
        s1 += v * lin_w[3072 + e];
        s2 += v * lin_w[1536 + e];
        s3 += v * lin_w[4608 + e];
    }
    for (int off = 32; off; off >>= 1) {
        s0 += __shfl_down(s0, off); s1 += __shfl_down(s1, off);
        s2 += __shfl_down(s2, off); s3 += __shfl_down(s3, off);
    }
    __shared__ float r[4][4];
    int w = t >> 6;
    if ((t & 63) == 0) { r[0][w] = s0; r[1][w] = s1; r[2][w] = s2; r[3][w] = s3; }
    __syncthreads();
    if (t == 0) {
        float t0 = 0.f, t1 = 0.f, t2 = 0.f, t3 = 0.f;
        for (int k = 0; k < 4; ++k) { t0 += r[0][k]; t1 += r[1][k]; t2 += r[2][k]; t3 += r[3][k]; }
        a[i * 2 + 0] = t0 + lin_b[0];
        a[i * 2 + 1] = t1 + lin_b[1];
        c[i * 2 + 0] = t2;
        c[i * 2 + 1] = t3;
    }
}

__global__ __launch_bounds__(384) void head_probs(
    const float* __restrict__ a, const float* __restrict__ c,
    const int* __restrict__ gt, float* __restrict__ probs,
    float* __restrict__ rowsum, float* __restrict__ rowcell)
{
    const int i = blockIdx.x, j = threadIdx.x;
    float l0 = a[i * 2 + 0] + c[j * 2 + 0];
    float l1 = a[i * 2 + 1] + c[j * 2 + 1];
    float m = fmaxf(l0, l1);
    float e0 = __expf(l0 - m), e1 = __expf(l1 - m);
    float inv = 1.f / (e0 + e1);
    float p0 = e0 * inv, p1 = e1 * inv;
    long base = ((long)i * NTOK + j) * 2;
    probs[base] = p0;
    probs[base + 1] = p1;
    float m2 = fmaxf(p0, p1);
    float z = m2 + __logf(__expf(p0 - m2) + __expf(p1 - m2));
    int g = gt[i * NTOK + j];
    float cell = z - (g ? p1 : p0);
    float cs = cell, ps = p1;
    for (int off = 32; off; off >>= 1) { cs += __shfl_down(cs, off); ps += __shfl_down(ps, off); }
    __shared__ float rc[6], rs[6];
    int w = j >> 6;
    if ((j & 63) == 0) { rc[w] = cs; rs[w] = ps; }
    __syncthreads();
    if (j == 0) {
        float csum = 0.f, psum = 0.f;
        for (int k = 0; k < 6; ++k) { csum += rc[k]; psum += rs[k]; }
        rowcell[i] = csum * (1.f / NTOK);
        rowsum[i] = psum;
    }
}

__global__ __launch_bounds__(64) void colsum_k(const float* __restrict__ probs,
                                               float* __restrict__ colsum)
{
    const int j = blockIdx.x, t = threadIdx.x;
    float s = 0.f;
    for (int i = t; i < NTOK; i += 64)
        s += probs[((long)i * NTOK + j) * 2 + 1];
    for (int off = 32; off; off >>= 1) s += __shfl_down(s, off);
    if (t == 0) colsum[j] = s;
}

__global__ __launch_bounds__(384) void finalize_k(
    const float* __restrict__ rowcell, const float* __restrict__ rowsum,
    const float* __restrict__ colsum, float* __restrict__ out)
{
    const int t = threadIdx.x;
    float cls = rowcell[t];
    float ee = (t < NTOK - 1) ? fabsf(rowsum[t] + colsum[t] - 1.f) : 0.f;
    for (int off = 32; off; off >>= 1) { cls += __shfl_down(cls, off); ee += __shfl_down(ee, off); }
    __shared__ float rc[6], re[6];
    int w = t >> 6;
    if ((t & 63) == 0) { rc[w] = cls; re[w] = ee; }
    __syncthreads();
    if (t == 0) {
        float a = 0.f, b = 0.f;
        for (int k = 0; k < 6; ++k) { a += rc[k]; b += re[k]; }
        out[NTOK * NTOK * 2 + 0] = a;
        out[NTOK * NTOK * 2 + 1] = b;
    }
}

// ---------------------------------------------------------------------------
// host-side encoder driver (bf16 weights, LDS-staged MFMA GEMM)
// ---------------------------------------------------------------------------
static void run_encoder(float* x, unsigned short* xb, int d,
                        const unsigned short* wq, const unsigned short* wo,
                        const unsigned short* w1, const unsigned short* w2,
                        const float* qkv_b, const float* out_b,
                        const float* ln1_s, const float* ln1_b,
                        const float* ff1_b, const float* ff2_b,
                        const float* ln2_s, const float* ln2_b,
                        unsigned short* qkvb, unsigned short* vtb,
                        unsigned short* ob, unsigned short* t1b, float* t2,
                        hipStream_t stream)
{
    const int dq = 3 * d;
    const int hd = d / HEADS;
    const float scale = 1.0f / sqrtf((float)hd);
    for (int l = 0; l < 2; ++l) {
        // qkv = x @ Wqkv^T + b (bf16 out; V block written transposed to vtb)
        gemm_bf16<<<dim3(dq / 128, 3), 256, 0, stream>>>(
            xb, wq + (long)l * dq * d, qkv_b + l * dq, qkvb,
            d, dq, 0, 1, vtb, 2 * d);
        // fused attention -> ob
        if (hd == 192)
            attn_fused<192><<<dim3(NTOK / 64, HEADS), 256, 0, stream>>>(
                qkvb, vtb, ob, scale);
        else
            attn_fused<384><<<dim3(NTOK / 64, HEADS), 256, 0, stream>>>(
                qkvb, vtb, ob, scale);
        // out-proj (fp32 out) + LN
        gemm_bf16<<<dim3(d / 128, 3), 256, 0, stream>>>(
            ob, wo + (long)l * d * d, out_b + l * d, t2,
            d, d, 0, 0, nullptr, 0);
        add_ln<<<NTOK, 256, 0, stream>>>(x, xb, t2, ln1_s + l * d, ln1_b + l * d, d);
        // ff1 (relu, bf16 out), ff2 (fp32 out) + LN
        gemm_bf16<<<dim3(2048 / 128, 3), 256, 0, stream>>>(
            xb, w1 + (long)l * 2048 * d, ff1_b + l * 2048, t1b,
            d, 2048, 1, 1, nullptr, 0);
        gemm_bf16<<<dim3(d / 128, 3), 256, 0, stream>>>(
            t1b, w2 + (long)l * d * 2048, ff2_b + l * d, t2,
            2048, d, 0, 0, nullptr, 0);
        add_ln<<<NTOK, 256, 0, stream>>>(x, xb, t2, ln2_s + l * d, ln2_b + l * d, d);
    }
}

extern "C" void kernel_launch(void* const* d_in, const int* in_sizes, int n_in,
                              void* d_out, int out_size, void* d_ws, size_t ws_size,
                              hipStream_t stream)
{
    const float* text_emb   = (const float*)d_in[0];
    const float* vision_emb = (const float*)d_in[1];
    const int*   gt         = (const int*)  d_in[2];
    const float* t_qkv_w = (const float*)d_in[3];
    const float* t_qkv_b = (const float*)d_in[4];
    const float* t_out_w = (const float*)d_in[5];
    const float* t_out_b = (const float*)d_in[6];
    const float* t_ln1_s = (const float*)d_in[7];
    const float* t_ln1_b = (const float*)d_in[8];
    const float* t_ff1_w = (const float*)d_in[9];
    const float* t_ff1_b = (const float*)d_in[10];
    const float* t_ff2_w = (const float*)d_in[11];
    const float* t_ff2_b = (const float*)d_in[12];
    const float* t_ln2_s = (const float*)d_in[13];
    const float* t_ln2_b = (const float*)d_in[14];
    const float* c_qkv_w = (const float*)d_in[15];
    const float* c_qkv_b = (const float*)d_in[16];
    const float* c_out_w = (const float*)d_in[17];
    const float* c_out_b = (const float*)d_in[18];
    const float* c_ln1_s = (const float*)d_in[19];
    const float* c_ln1_b = (const float*)d_in[20];
    const float* c_ff1_w = (const float*)d_in[21];
    const float* c_ff1_b = (const float*)d_in[22];
    const float* c_ff2_w = (const float*)d_in[23];
    const float* c_ff2_b = (const float*)d_in[24];
    const float* c_ln2_s = (const float*)d_in[25];
    const float* c_ln2_b = (const float*)d_in[26];
    const float* lin_w   = (const float*)d_in[27];
    const float* lin_b   = (const float*)d_in[28];
    float* out = (float*)d_out;

    // ---- workspace layout ----
    float* ws = (float*)d_ws;
    float* xt      = ws;                 // 384*768
    float* all     = xt + 294912;        // 384*1536
    float* t2      = all + 589824;       // 384*1536 (max)
    float* abuf    = t2 + 589824;
    float* cbuf    = abuf + 768;
    float* rowsum  = cbuf + 768;
    float* rowcell = rowsum + 384;
    float* colsum  = rowcell + 384;      // fp32 total 1477248
    unsigned short* ub = (unsigned short*)(ws + 1477248);
    unsigned short* xtb   = ub;                  // 294912
    unsigned short* allb  = xtb + 294912;        // 589824
    unsigned short* qkvb  = allb + 589824;       // 384*4608
    unsigned short* vtb   = qkvb + 1769472;      // 1536*384 (max)
    unsigned short* ob    = vtb + 589824;        // 589824
    unsigned short* t1b   = ob + 589824;         // 384*2048
    unsigned short* wb    = t1b + 786432;        // 42467328 bf16 weights

    // ---- weight conversion (one fused launch) ----
    convert_weights<<<(WTOT / 4 + 255) / 256, 256, 0, stream>>>(
        t_qkv_w, t_out_w, t_ff1_w, t_ff2_w,
        c_qkv_w, c_out_w, c_ff1_w, c_ff2_w, wb);

    // ---- text encoder (d = 768) ----
    initx_k<<<(294912 + 255) / 256, 256, 0, stream>>>(text_emb, xt, xtb, 294912);
    run_encoder(xt, xtb, 768,
                wb + WO0, wb + WO1, wb + WO2, wb + WO3,
                t_qkv_b, t_out_b, t_ln1_s, t_ln1_b,
                t_ff1_b, t_ff2_b, t_ln2_s, t_ln2_b,
                qkvb, vtb, ob, t1b, t2, stream);

    // ---- concat -> combined encoder (d = 1536) ----
    concat_k<<<(589824 + 255) / 256, 256, 0, stream>>>(xt, vision_emb, all, allb);
    run_encoder(all, allb, 1536,
                wb + WO4, wb + WO5, wb + WO6, wb + WO7,
                c_qkv_b, c_out_b, c_ln1_s, c_ln1_b,
                c_ff1_b, c_ff2_b, c_ln2_s, c_ln2_b,
                qkvb, vtb, ob, t1b, t2, stream);

    // ---- head ----
    head_ac<<<NTOK, 256, 0, stream>>>(all, lin_w, lin_b, abuf, cbuf);
    head_probs<<<NTOK, 384, 0, stream>>>(abuf, cbuf, gt, out, rowsum, rowcell);
    colsum_k<<<NTOK, 64, 0, stream>>>(out, colsum);
    finalize_k<<<1, 384, 0, stream>>>(rowcell, rowsum, colsum, out);
}

// Round 6
// 598.397 us; speedup vs baseline: 3.1477x; 1.4259x over previous
//
#include <hip/hip_runtime.h>
#include <hip/hip_bf16.h>
#include <math.h>

#define NTOK 384
#define HEADS 4

typedef __attribute__((ext_vector_type(8))) short bf16x8;
typedef __attribute__((ext_vector_type(4))) float f32x4;

__device__ __forceinline__ unsigned short f2b(float f) {
    union { float f; unsigned int u; } v; v.f = f;
    unsigned int r = (v.u + 0x7fff + ((v.u >> 16) & 1)) >> 16;  // RNE
    return (unsigned short)r;
}

// async 16B global -> LDS (wave-uniform LDS base; HW adds lane*16)
__device__ __forceinline__ void g2l16(const void* g, void* l) {
    __builtin_amdgcn_global_load_lds(
        (const __attribute__((address_space(1))) unsigned int*)g,
        (__attribute__((address_space(3))) unsigned int*)l, 16, 0, 0);
}

// ---------------------------------------------------------------------------
// 64x64-tile MFMA bf16 GEMM, batched over z. C = A@B^T + bias, opt relu,
// fp32/bf16 out, optional transposed-V epilogue for col0 >= dv2.
// Block 256 thr = 4 waves (2x2, 32x32 each). BK=32, double-buffered LDS via
// global_load_lds; 64B LDS rows, 16B chunks rotated by (row>>1)&3.
// ---------------------------------------------------------------------------
__device__ __forceinline__ void stage64(
    const unsigned short* __restrict__ g, int row0, int k0, int ld,
    char* region, int wid, int lane)
{
    int c = wid * 64 + lane;                 // chunk 0..255
    int row = c >> 2, p = c & 3;
    int kc = (p - (row >> 1)) & 3;
    g2l16(g + (long)(row0 + row) * ld + k0 + kc * 8,
          region + (wid * 64) * 16);         // wave-uniform base
}

__global__ __launch_bounds__(256, 4) void gemm64(
    const unsigned short* __restrict__ A, const unsigned short* __restrict__ B,
    const float* __restrict__ bias, void* __restrict__ Cv,
    int K, int lda, int ldb, int ldc,
    long sA, long sB, long sC, int relu, int out_bf16,
    unsigned short* __restrict__ vt, int dv2)
{
    __shared__ char smem[2][8192];           // per buf: A 4KB | B 4KB
    A += (long)blockIdx.z * sA;
    B += (long)blockIdx.z * sB;
    const int t = threadIdx.x, lane = t & 63, wid = t >> 6;
    const int wm = wid >> 1, wn = wid & 1;
    const int r16 = lane & 15, quad = lane >> 4;
    const int row0 = blockIdx.y * 64, col0 = blockIdx.x * 64;

    f32x4 acc[2][2] = {};

    stage64(A, row0, 0, lda, smem[0], wid, lane);
    stage64(B, col0, 0, ldb, smem[0] + 4096, wid, lane);
    int buf = 0;

    for (int k0 = 0; k0 < K; k0 += 32) {
        __syncthreads();
        if (k0 + 32 < K) {
            stage64(A, row0, k0 + 32, lda, smem[buf ^ 1], wid, lane);
            stage64(B, col0, k0 + 32, ldb, smem[buf ^ 1] + 4096, wid, lane);
        }
        const char* cb = smem[buf];
        bf16x8 af[2], bfv[2];
        #pragma unroll
        for (int rt = 0; rt < 2; ++rt) {
            int row = wm * 32 + rt * 16 + r16;
            int p = (quad + (row >> 1)) & 3;
            af[rt] = *reinterpret_cast<const bf16x8*>(cb + row * 64 + p * 16);
        }
        #pragma unroll
        for (int ct = 0; ct < 2; ++ct) {
            int col = wn * 32 + ct * 16 + r16;
            int p = (quad + (col >> 1)) & 3;
            bfv[ct] = *reinterpret_cast<const bf16x8*>(cb + 4096 + col * 64 + p * 16);
        }
        #pragma unroll
        for (int rt = 0; rt < 2; ++rt)
            #pragma unroll
            for (int ct = 0; ct < 2; ++ct)
                acc[rt][ct] = __builtin_amdgcn_mfma_f32_16x16x32_bf16(
                    af[rt], bfv[ct], acc[rt][ct], 0, 0, 0);
        buf ^= 1;
    }

    float* Cf = (float*)Cv;
    unsigned short* Cb = (unsigned short*)Cv;
    const long zoff = (long)blockIdx.z * sC;
    const int vwrite = (vt != nullptr) && (col0 >= dv2);
    #pragma unroll
    for (int rt = 0; rt < 2; ++rt) {
        #pragma unroll
        for (int ct = 0; ct < 2; ++ct) {
            f32x4 v = acc[rt][ct];
            int col = col0 + wn * 32 + ct * 16 + r16;
            float bi = bias ? bias[col] : 0.f;
            #pragma unroll
            for (int i = 0; i < 4; ++i) {
                v[i] += bi;
                if (relu) v[i] = fmaxf(v[i], 0.f);
            }
            int rbase = row0 + wm * 32 + rt * 16 + quad * 4;
            if (vwrite) {
                ushort4 p;
                p.x = f2b(v[0]); p.y = f2b(v[1]); p.z = f2b(v[2]); p.w = f2b(v[3]);
                *reinterpret_cast<ushort4*>(vt + (long)(col - dv2) * NTOK + rbase) = p;
            } else if (out_bf16) {
                #pragma unroll
                for (int i = 0; i < 4; ++i)
                    Cb[zoff + (long)(rbase + i) * ldc + col] = f2b(v[i]);
            } else {
                #pragma unroll
                for (int i = 0; i < 4; ++i)
                    Cf[zoff + (long)(rbase + i) * ldc + col] = v[i];
            }
        }
    }
}

// ---------------------------------------------------------------------------
// Fused fp32 -> bf16 conversion of all 8 weight tensors. 32B read / 16B
// write per thread.
// ---------------------------------------------------------------------------
#define WO0 0u
#define WO1 3538944u
#define WO2 4718592u
#define WO3 7864320u
#define WO4 11010048u
#define WO5 25165824u
#define WO6 29884416u
#define WO7 36175872u
#define WTOT 42467328u

__global__ __launch_bounds__(256) void convert_weights(
    const float* __restrict__ s0, const float* __restrict__ s1,
    const float* __restrict__ s2, const float* __restrict__ s3,
    const float* __restrict__ s4, const float* __restrict__ s5,
    const float* __restrict__ s6, const float* __restrict__ s7,
    unsigned short* __restrict__ dst)
{
    unsigned int e = (blockIdx.x * 256u + threadIdx.x) * 8u;
    if (e >= WTOT) return;
    const float* src; unsigned int local;
    if      (e < WO1) { src = s0; local = e - WO0; }
    else if (e < WO2) { src = s1; local = e - WO1; }
    else if (e < WO3) { src = s2; local = e - WO2; }
    else if (e < WO4) { src = s3; local = e - WO3; }
    else if (e < WO5) { src = s4; local = e - WO4; }
    else if (e < WO6) { src = s5; local = e - WO5; }
    else if (e < WO7) { src = s6; local = e - WO6; }
    else              { src = s7; local = e - WO7; }
    float4 v0 = *reinterpret_cast<const float4*>(src + local);
    float4 v1 = *reinterpret_cast<const float4*>(src + local + 4);
    uint4 o;
    o.x = (unsigned)f2b(v0.x) | ((unsigned)f2b(v0.y) << 16);
    o.y = (unsigned)f2b(v0.z) | ((unsigned)f2b(v0.w) << 16);
    o.z = (unsigned)f2b(v1.x) | ((unsigned)f2b(v1.y) << 16);
    o.w = (unsigned)f2b(v1.z) | ((unsigned)f2b(v1.w) << 16);
    *reinterpret_cast<uint4*>(dst + e) = o;
}

// ---------------------------------------------------------------------------
// Softmax over rows of length 384 (one wave per row); fp32 in, bf16 out.
// ---------------------------------------------------------------------------
__global__ __launch_bounds__(64) void softmax_rows(
    const float* __restrict__ S, unsigned short* __restrict__ P, float scale)
{
    const float* p = S + (long)blockIdx.x * NTOK;
    unsigned short* q = P + (long)blockIdx.x * NTOK;
    const int t = threadIdx.x;
    float vals[6];
    float vmax = -1e30f;
    #pragma unroll
    for (int i = 0; i < 6; ++i) {
        vals[i] = p[t + i * 64] * scale;
        vmax = fmaxf(vmax, vals[i]);
    }
    for (int off = 32; off; off >>= 1) vmax = fmaxf(vmax, __shfl_down(vmax, off));
    vmax = __shfl(vmax, 0);
    float sum = 0.f;
    #pragma unroll
    for (int i = 0; i < 6; ++i) { vals[i] = __expf(vals[i] - vmax); sum += vals[i]; }
    for (int off = 32; off; off >>= 1) sum += __shfl_down(sum, off);
    sum = __shfl(sum, 0);
    float inv = 1.f / sum;
    #pragma unroll
    for (int i = 0; i < 6; ++i) q[t + i * 64] = f2b(vals[i] * inv);
}

// ---------------------------------------------------------------------------
// x = LayerNorm(x + y) * s + b  (fp32), also writes bf16 copy xb.
// ---------------------------------------------------------------------------
__global__ __launch_bounds__(256) void add_ln(
    float* __restrict__ x, unsigned short* __restrict__ xb,
    const float* __restrict__ y,
    const float* __restrict__ s, const float* __restrict__ b, int d)
{
    float* xr = x + (long)blockIdx.x * d;
    unsigned short* xbr = xb + (long)blockIdx.x * d;
    const float* yr = y + (long)blockIdx.x * d;
    const int t = threadIdx.x;
    float s1 = 0.f, s2 = 0.f;
    for (int i = t; i < d; i += 256) {
        float v = xr[i] + yr[i];
        s1 += v; s2 += v * v;
    }
    for (int off = 32; off; off >>= 1) { s1 += __shfl_down(s1, off); s2 += __shfl_down(s2, off); }
    __shared__ float r1[4], r2[4];
    int w = t >> 6;
    if ((t & 63) == 0) { r1[w] = s1; r2[w] = s2; }
    __syncthreads();
    if (t == 0) {
        float a = 0.f, c = 0.f;
        for (int i = 0; i < 4; ++i) { a += r1[i]; c += r2[i]; }
        r1[0] = a; r2[0] = c;
    }
    __syncthreads();
    float mean = r1[0] / d;
    float var = r2[0] / d - mean * mean;
    float rstd = rsqrtf(var + 1e-5f);
    for (int i = t; i < d; i += 256) {
        float v = (xr[i] + yr[i] - mean) * rstd * s[i] + b[i];
        xr[i] = v;
        xbr[i] = f2b(v);
    }
}

// ---------------------------------------------------------------------------
// init / concat (write fp32 + bf16 copies)
// ---------------------------------------------------------------------------
__global__ void initx_k(const float* __restrict__ src, float* __restrict__ dst,
                        unsigned short* __restrict__ dstb, int n)
{
    int i = blockIdx.x * blockDim.x + threadIdx.x;
    if (i < n) { float v = src[i]; dst[i] = v; dstb[i] = f2b(v); }
}

__global__ void concat_k(const float* __restrict__ te, const float* __restrict__ ve,
                         float* __restrict__ all, unsigned short* __restrict__ allb)
{
    int i = blockIdx.x * blockDim.x + threadIdx.x;
    if (i >= NTOK * 1536) return;
    int r = i / 1536, c = i % 1536;
    float v = (c < 768) ? te[r * 768 + c] : ve[r * 768 + (c - 768)];
    all[i] = v;
    allb[i] = f2b(v);
}

// ---------------------------------------------------------------------------
// head kernels (fp32)
// ---------------------------------------------------------------------------
__global__ __launch_bounds__(256) void head_ac(
    const float* __restrict__ all, const float* __restrict__ lin_w,
    const float* __restrict__ lin_b, float* __restrict__ a, float* __restrict__ c)
{
    const int i = blockIdx.x, t = threadIdx.x;
    const float* xr = all + (long)i * 1536;
    float s0 = 0.f, s1 = 0.f, s2 = 0.f, s3 = 0.f;
    for (int e = t; e < 1536; e += 256) {
        float v = xr[e];
        s0 += v * lin_w[e];
        s1 += v * lin_w[3072 + e];
        s2 += v * lin_w[1536 + e];
        s3 += v * lin_w[4608 + e];
    }
    for (int off = 32; off; off >>= 1) {
        s0 += __shfl_down(s0, off); s1 += __shfl_down(s1, off);
        s2 += __shfl_down(s2, off); s3 += __shfl_down(s3, off);
    }
    __shared__ float r[4][4];
    int w = t >> 6;
    if ((t & 63) == 0) { r[0][w] = s0; r[1][w] = s1; r[2][w] = s2; r[3][w] = s3; }
    __syncthreads();
    if (t == 0) {
        float t0 = 0.f, t1 = 0.f, t2 = 0.f, t3 = 0.f;
        for (int k = 0; k < 4; ++k) { t0 += r[0][k]; t1 += r[1][k]; t2 += r[2][k]; t3 += r[3][k]; }
        a[i * 2 + 0] = t0 + lin_b[0];
        a[i * 2 + 1] = t1 + lin_b[1];
        c[i * 2 + 0] = t2;
        c[i * 2 + 1] = t3;
    }
}

__global__ __launch_bounds__(384) void head_probs(
    const float* __restrict__ a, const float* __restrict__ c,
    const int* __restrict__ gt, float* __restrict__ probs,
    float* __restrict__ rowsum, float* __restrict__ rowcell)
{
    const int i = blockIdx.x, j = threadIdx.x;
    float l0 = a[i * 2 + 0] + c[j * 2 + 0];
    float l1 = a[i * 2 + 1] + c[j * 2 + 1];
    float m = fmaxf(l0, l1);
    float e0 = __expf(l0 - m), e1 = __expf(l1 - m);
    float inv = 1.f / (e0 + e1);
    float p0 = e0 * inv, p1 = e1 * inv;
    long base = ((long)i * NTOK + j) * 2;
    probs[base] = p0;
    probs[base + 1] = p1;
    float m2 = fmaxf(p0, p1);
    float z = m2 + __logf(__expf(p0 - m2) + __expf(p1 - m2));
    int g = gt[i * NTOK + j];
    float cell = z - (g ? p1 : p0);
    float cs = cell, ps = p1;
    for (int off = 32; off; off >>= 1) { cs += __shfl_down(cs, off); ps += __shfl_down(ps, off); }
    __shared__ float rc[6], rs[6];
    int w = j >> 6;
    if ((j & 63) == 0) { rc[w] = cs; rs[w] = ps; }
    __syncthreads();
    if (j == 0) {
        float csum = 0.f, psum = 0.f;
        for (int k = 0; k < 6; ++k) { csum += rc[k]; psum += rs[k]; }
        rowcell[i] = csum * (1.f / NTOK);
        rowsum[i] = psum;
    }
}

__global__ __launch_bounds__(64) void colsum_k(const float* __restrict__ probs,
                                               float* __restrict__ colsum)
{
    const int j = blockIdx.x, t = threadIdx.x;
    float s = 0.f;
    for (int i = t; i < NTOK; i += 64)
        s += probs[((long)i * NTOK + j) * 2 + 1];
    for (int off = 32; off; off >>= 1) s += __shfl_down(s, off);
    if (t == 0) colsum[j] = s;
}

__global__ __launch_bounds__(384) void finalize_k(
    const float* __restrict__ rowcell, const float* __restrict__ rowsum,
    const float* __restrict__ colsum, float* __restrict__ out)
{
    const int t = threadIdx.x;
    float cls = rowcell[t];
    float ee = (t < NTOK - 1) ? fabsf(rowsum[t] + colsum[t] - 1.f) : 0.f;
    for (int off = 32; off; off >>= 1) { cls += __shfl_down(cls, off); ee += __shfl_down(ee, off); }
    __shared__ float rc[6], re[6];
    int w = t >> 6;
    if ((t & 63) == 0) { rc[w] = cls; re[w] = ee; }
    __syncthreads();
    if (t == 0) {
        float a = 0.f, b = 0.f;
        for (int k = 0; k < 6; ++k) { a += rc[k]; b += re[k]; }
        out[NTOK * NTOK * 2 + 0] = a;
        out[NTOK * NTOK * 2 + 1] = b;
    }
}

// ---------------------------------------------------------------------------
// host-side encoder driver (bf16 weights, 64-tile staged gemms)
// ---------------------------------------------------------------------------
static void run_encoder(float* x, unsigned short* xb, int d,
                        const unsigned short* wq, const unsigned short* wo,
                        const unsigned short* w1, const unsigned short* w2,
                        const float* qkv_b, const float* out_b,
                        const float* ln1_s, const float* ln1_b,
                        const float* ff1_b, const float* ff2_b,
                        const float* ln2_s, const float* ln2_b,
                        unsigned short* qkvb, float* sc, unsigned short* attnb,
                        unsigned short* vtb, unsigned short* ob,
                        unsigned short* t1b, float* t2,
                        hipStream_t stream)
{
    const int dq = 3 * d;
    const int hd = d / HEADS;
    const float scale = 1.0f / sqrtf((float)hd);
    for (int l = 0; l < 2; ++l) {
        // qkv = x @ Wqkv^T + b (bf16; V block written transposed to vtb)
        gemm64<<<dim3(dq / 64, 6), 256, 0, stream>>>(
            xb, wq + (long)l * dq * d, qkv_b + l * dq, qkvb,
            d, d, d, dq, 0, 0, 0, 0, 1, vtb, 2 * d);
        // scores = Q @ K^T (fp32), batched over heads
        gemm64<<<dim3(6, 6, HEADS), 256, 0, stream>>>(
            qkvb, qkvb + d, nullptr, sc,
            hd, dq, dq, NTOK, (long)hd, (long)hd, (long)NTOK * NTOK,
            0, 0, nullptr, 0);
        softmax_rows<<<HEADS * NTOK, 64, 0, stream>>>(sc, attnb, scale);
        // o = attn @ V^T (bf16), batched over heads
        gemm64<<<dim3(hd / 64, 6, HEADS), 256, 0, stream>>>(
            attnb, vtb, nullptr, ob,
            NTOK, NTOK, NTOK, d, (long)NTOK * NTOK, (long)hd * NTOK, (long)hd,
            0, 1, nullptr, 0);
        // out-proj (fp32) + LN
        gemm64<<<dim3(d / 64, 6), 256, 0, stream>>>(
            ob, wo + (long)l * d * d, out_b + l * d, t2,
            d, d, d, d, 0, 0, 0, 0, 0, nullptr, 0);
        add_ln<<<NTOK, 256, 0, stream>>>(x, xb, t2, ln1_s + l * d, ln1_b + l * d, d);
        // ff1 (relu, bf16), ff2 (fp32) + LN
        gemm64<<<dim3(2048 / 64, 6), 256, 0, stream>>>(
            xb, w1 + (long)l * 2048 * d, ff1_b + l * 2048, t1b,
            d, d, d, 2048, 0, 0, 0, 1, 1, nullptr, 0);
        gemm64<<<dim3(d / 64, 6), 256, 0, stream>>>(
            t1b, w2 + (long)l * d * 2048, ff2_b + l * d, t2,
            2048, 2048, 2048, d, 0, 0, 0, 0, 0, nullptr, 0);
        add_ln<<<NTOK, 256, 0, stream>>>(x, xb, t2, ln2_s + l * d, ln2_b + l * d, d);
    }
}

extern "C" void kernel_launch(void* const* d_in, const int* in_sizes, int n_in,
                              void* d_out, int out_size, void* d_ws, size_t ws_size,
                              hipStream_t stream)
{
    const float* text_emb   = (const float*)d_in[0];
    const float* vision_emb = (const float*)d_in[1];
    const int*   gt         = (const int*)  d_in[2];
    const float* t_qkv_w = (const float*)d_in[3];
    const float* t_qkv_b = (const float*)d_in[4];
    const float* t_out_w = (const float*)d_in[5];
    const float* t_out_b = (const float*)d_in[6];
    const float* t_ln1_s = (const float*)d_in[7];
    const float* t_ln1_b = (const float*)d_in[8];
    const float* t_ff1_w = (const float*)d_in[9];
    const float* t_ff1_b = (const float*)d_in[10];
    const float* t_ff2_w = (const float*)d_in[11];
    const float* t_ff2_b = (const float*)d_in[12];
    const float* t_ln2_s = (const float*)d_in[13];
    const float* t_ln2_b = (const float*)d_in[14];
    const float* c_qkv_w = (const float*)d_in[15];
    const float* c_qkv_b = (const float*)d_in[16];
    const float* c_out_w = (const float*)d_in[17];
    const float* c_out_b = (const float*)d_in[18];
    const float* c_ln1_s = (const float*)d_in[19];
    const float* c_ln1_b = (const float*)d_in[20];
    const float* c_ff1_w = (const float*)d_in[21];
    const float* c_ff1_b = (const float*)d_in[22];
    const float* c_ff2_w = (const float*)d_in[23];
    const float* c_ff2_b = (const float*)d_in[24];
    const float* c_ln2_s = (const float*)d_in[25];
    const float* c_ln2_b = (const float*)d_in[26];
    const float* lin_w   = (const float*)d_in[27];
    const float* lin_b   = (const float*)d_in[28];
    float* out = (float*)d_out;

    // ---- workspace layout ----
    float* ws = (float*)d_ws;
    float* xt      = ws;                 // 384*768
    float* all     = xt + 294912;        // 384*1536
    float* t2      = all + 589824;       // 384*1536 (max)
    float* sc      = t2 + 589824;        // 4*384*384 fp32
    float* abuf    = sc + 589824;
    float* cbuf    = abuf + 768;
    float* rowsum  = cbuf + 768;
    float* rowcell = rowsum + 384;
    float* colsum  = rowcell + 384;      // fp32 total 2067072
    unsigned short* ub = (unsigned short*)(ws + 2067072);
    unsigned short* xtb   = ub;                  // 294912
    unsigned short* allb  = xtb + 294912;        // 589824
    unsigned short* qkvb  = allb + 589824;       // 384*4608
    unsigned short* attnb = qkvb + 1769472;      // 4*384*384
    unsigned short* vtb   = attnb + 589824;      // 1536*384 (max)
    unsigned short* ob    = vtb + 589824;        // 589824
    unsigned short* t1b   = ob + 589824;         // 384*2048
    unsigned short* wb    = t1b + 786432;        // 42467328 bf16 weights

    // ---- weight conversion (one fused launch) ----
    convert_weights<<<(WTOT / 8 + 255) / 256, 256, 0, stream>>>(
        t_qkv_w, t_out_w, t_ff1_w, t_ff2_w,
        c_qkv_w, c_out_w, c_ff1_w, c_ff2_w, wb);

    // ---- text encoder (d = 768) ----
    initx_k<<<(294912 + 255) / 256, 256, 0, stream>>>(text_emb, xt, xtb, 294912);
    run_encoder(xt, xtb, 768,
                wb + WO0, wb + WO1, wb + WO2, wb + WO3,
                t_qkv_b, t_out_b, t_ln1_s, t_ln1_b,
                t_ff1_b, t_ff2_b, t_ln2_s, t_ln2_b,
                qkvb, sc, attnb, vtb, ob, t1b, t2, stream);

    // ---- concat -> combined encoder (d = 1536) ----
    concat_k<<<(589824 + 255) / 256, 256, 0, stream>>>(xt, vision_emb, all, allb);
    run_encoder(all, allb, 1536,
                wb + WO4, wb + WO5, wb + WO6, wb + WO7,
                c_qkv_b, c_out_b, c_ln1_s, c_ln1_b,
                c_ff1_b, c_ff2_b, c_ln2_s, c_ln2_b,
                qkvb, sc, attnb, vtb, ob, t1b, t2, stream);

    // ---- head ----
    head_ac<<<NTOK, 256, 0, stream>>>(all, lin_w, lin_b, abuf, cbuf);
    head_probs<<<NTOK, 384, 0, stream>>>(abuf, cbuf, gt, out, rowsum, rowcell);
    colsum_k<<<NTOK, 64, 0, stream>>>(out, colsum);
    finalize_k<<<1, 384, 0, stream>>>(rowcell, rowsum, colsum, out);
}